// Round 10
// baseline (975.213 us; speedup 1.0000x reference)
//
#include <hip/hip_runtime.h>

#define C  64
#define KK 27
#define BB 4

typedef _Float16 h8 __attribute__((ext_vector_type(8)));
typedef float    f4 __attribute__((ext_vector_type(4)));

// ===================== fast-path ws layout (float offsets) =====================
//      0 : pooled[256]
//    256 : counts[4]
//    260 : gate[256]
//    516 : bnscale[64]
//    580 : bnshift[64]
//   1024 : Wf1[27*4096 halfs]  (55296 floats)
//  56320 : Wf2[27*4096 halfs]  (55296 floats)
// 114688 : xg[N*64 halfs]  (N*32 floats)
// 114688+N*32 : h2[N*64 halfs]  (N*32 floats)
#define XG_OFF 114688

__global__ __launch_bounds__(256) void init_ws(float* ws) {
  int t = blockIdx.x * 256 + threadIdx.x;
  if (t < 1024) ws[t] = 0.f;
}

// Grid-strided pooling: 16 threads per point row, float4 loads, shuffle+LDS reduce.
__global__ __launch_bounds__(256) void pool_kernel(
    const float4* __restrict__ x4, const int* __restrict__ bidx,
    float* __restrict__ pooled, float* __restrict__ counts, int N)
{
  int t = threadIdx.x;
  int g = t & 15;
  int rowInBlk = t >> 4;
  int lane = t & 63, wv = t >> 6;
  float4 acc[BB];
#pragma unroll
  for (int b = 0; b < BB; ++b) acc[b] = make_float4(0.f, 0.f, 0.f, 0.f);
  int cnt[BB] = {0, 0, 0, 0};
  for (int n = blockIdx.x * 16 + rowInBlk; n < N; n += gridDim.x * 16) {
    int b = bidx[n];
    float4 v = x4[((size_t)n << 4) + g];
    if (b == 0)      { acc[0].x += v.x; acc[0].y += v.y; acc[0].z += v.z; acc[0].w += v.w; }
    else if (b == 1) { acc[1].x += v.x; acc[1].y += v.y; acc[1].z += v.z; acc[1].w += v.w; }
    else if (b == 2) { acc[2].x += v.x; acc[2].y += v.y; acc[2].z += v.z; acc[2].w += v.w; }
    else             { acc[3].x += v.x; acc[3].y += v.y; acc[3].z += v.z; acc[3].w += v.w; }
    if (g == 0) {
      if (b == 0) cnt[0]++; else if (b == 1) cnt[1]++;
      else if (b == 2) cnt[2]++; else cnt[3]++;
    }
  }
#pragma unroll
  for (int b = 0; b < BB; ++b) {
    acc[b].x += __shfl_xor(acc[b].x, 16); acc[b].y += __shfl_xor(acc[b].y, 16);
    acc[b].z += __shfl_xor(acc[b].z, 16); acc[b].w += __shfl_xor(acc[b].w, 16);
    acc[b].x += __shfl_xor(acc[b].x, 32); acc[b].y += __shfl_xor(acc[b].y, 32);
    acc[b].z += __shfl_xor(acc[b].z, 32); acc[b].w += __shfl_xor(acc[b].w, 32);
    cnt[b] += __shfl_xor(cnt[b], 16);
    cnt[b] += __shfl_xor(cnt[b], 32);
  }
  __shared__ float red[4][BB][16][4];
  __shared__ int cred[4][BB];
  if (lane < 16) {
#pragma unroll
    for (int b = 0; b < BB; ++b) {
      red[wv][b][lane][0] = acc[b].x; red[wv][b][lane][1] = acc[b].y;
      red[wv][b][lane][2] = acc[b].z; red[wv][b][lane][3] = acc[b].w;
    }
    if (lane == 0) {
#pragma unroll
      for (int b = 0; b < BB; ++b) cred[wv][b] = cnt[b];
    }
  }
  __syncthreads();
  {
    int b = t >> 6, rem = t & 63;
    int gg = rem >> 2, comp = rem & 3;
    float s = red[0][b][gg][comp] + red[1][b][gg][comp] +
              red[2][b][gg][comp] + red[3][b][gg][comp];
    if (s != 0.f) atomicAdd(&pooled[b * C + (gg << 2) + comp], s);
  }
  if (t < BB) {
    int s = cred[0][t] + cred[1][t] + cred[2][t] + cred[3][t];
    if (s) atomicAdd(&counts[t], (float)s);
  }
}

__global__ __launch_bounds__(256) void gate_kernel(
    const float* __restrict__ pooled, const float* __restrict__ counts,
    const float* __restrict__ w_fc1, const float* __restrict__ b_fc1,
    const float* __restrict__ w_fc2, const float* __restrict__ b_fc2,
    const float* __restrict__ bn_gamma, const float* __restrict__ bn_beta,
    const float* __restrict__ bn_mean, const float* __restrict__ bn_var,
    float* __restrict__ gate, float* __restrict__ bnscale, float* __restrict__ bnshift)
{
  __shared__ float mean[BB * C];
  __shared__ float hh[BB * 16];
  int t = threadIdx.x;
  { int b = t >> 6; mean[t] = pooled[t] / counts[b]; }
  __syncthreads();
  if (t < BB * 16) {
    int b = t >> 4, r = t & 15;
    float s = b_fc1[r];
    for (int c = 0; c < C; ++c) s += mean[b * C + c] * w_fc1[c * 16 + r];
    hh[t] = fmaxf(s, 0.f);
  }
  __syncthreads();
  {
    int b = t >> 6, c = t & 63;
    float s = b_fc2[c];
    for (int r = 0; r < 16; ++r) s += hh[b * 16 + r] * w_fc2[r * 64 + c];
    gate[t] = 1.f / (1.f + expf(-s));
  }
  if (t < C) {
    float sc = bn_gamma[t] * rsqrtf(bn_var[t] + 1e-5f);
    bnscale[t] = sc;
    bnshift[t] = bn_beta[t] - bn_mean[t] * sc;
  }
}

// ---------------- pack W into f16 fragment-major layout ----------------
// Fragment (kt,ct): lane = ((ci>>3)&3)*16 + (co&15), elem i = ci&7, kt = ci>>5, ct = co>>4.
// halfs addr = k*4096 + (kt*4+ct)*512 + lane*8 + i
__global__ __launch_bounds__(256) void w_pack(
    const float* __restrict__ W1, const float* __restrict__ W2,
    _Float16* __restrict__ Wf1, _Float16* __restrict__ Wf2)
{
  int kk = blockIdx.x;
  const float* src = (kk < KK) ? (W1 + ((size_t)kk << 12)) : (W2 + ((size_t)(kk - KK) << 12));
  _Float16* dst = (kk < KK) ? (Wf1 + ((size_t)kk << 12)) : (Wf2 + ((size_t)(kk - KK) << 12));
  int t = threadIdx.x;
  for (int e = 0; e < 16; ++e) {
    int idx = e * 256 + t;
    int ci = idx >> 6, co = idx & 63;
    int kt = ci >> 5, i = ci & 7, lh = (ci >> 3) & 3, ct = co >> 4, col = co & 15;
    int lane = lh * 16 + col;
    dst[((kt * 4 + ct) * 64 + lane) * 8 + i] = (_Float16)src[idx];
  }
}

// ---------------- materialize gated feats as f16 ----------------
__global__ __launch_bounds__(256) void xg_pack(
    const float* __restrict__ feats, const int* __restrict__ bidx,
    const float* __restrict__ gate, _Float16* __restrict__ xg, long nchunks)
{
  long i = (long)blockIdx.x * 256 + threadIdx.x;
  long stride = (long)gridDim.x * 256;
  for (; i < nchunks; i += stride) {
    long row = i >> 3; int c8 = (int)(i & 7) << 3;
    const float* x = feats + (row << 6) + c8;
    const float* g = gate + ((size_t)(bidx[row]) << 6) + c8;
    float4 v0 = *(const float4*)x;
    float4 v1 = *(const float4*)(x + 4);
    float4 g0 = *(const float4*)g;
    float4 g1 = *(const float4*)(g + 4);
    h8 o;
    o[0] = (_Float16)(v0.x * g0.x); o[1] = (_Float16)(v0.y * g0.y);
    o[2] = (_Float16)(v0.z * g0.z); o[3] = (_Float16)(v0.w * g0.w);
    o[4] = (_Float16)(v1.x * g1.x); o[5] = (_Float16)(v1.y * g1.y);
    o[6] = (_Float16)(v1.z * g1.z); o[7] = (_Float16)(v1.w * g1.w);
    *(h8*)(xg + (row << 6) + c8) = o;
  }
}

// ---------------- fused sparse-conv: per-wave 16 dst rows, k-loop, MFMA ----------------
// MODE 0: conv1 — src = xg (gated f16), epilogue BN+ReLU -> h2 (f16)
// MODE 1: conv2 — src = h2, epilogue +bias -> out (f32)
template <int MODE>
__global__ __launch_bounds__(256) void conv_fused(
    const _Float16* __restrict__ src, const _Float16* __restrict__ Wf,
    const int* __restrict__ nbr, const float* __restrict__ epA,
    const float* __restrict__ epB, _Float16* __restrict__ outh,
    float* __restrict__ outf, int N)
{
  int t = threadIdx.x, wv = t >> 6, lane = t & 63;
  int row = blockIdx.x * 64 + (wv << 4) + (lane & 15);   // A-operand dst row
  int koff = (lane >> 4) << 3;                            // K-slice within fragment
  f4 acc[4];
#pragma unroll
  for (int ct = 0; ct < 4; ++ct) acc[ct] = (f4){0.f, 0.f, 0.f, 0.f};
#pragma unroll 1
  for (int k = 0; k < KK; ++k) {
    int idx = (row < N) ? nbr[(size_t)k * N + row] : -1;
    if (__ballot(idx >= 0) == 0ull) continue;            // wave-uniform sparse skip
    h8 a0 = {}, a1 = {};
    if (idx >= 0) {
      const _Float16* xr = src + ((size_t)idx << 6);
      a0 = *(const h8*)(xr + koff);
      a1 = *(const h8*)(xr + 32 + koff);
    }
    const h8* Wb = (const h8*)(Wf + ((size_t)k << 12));
#pragma unroll
    for (int ct = 0; ct < 4; ++ct) {
      acc[ct] = __builtin_amdgcn_mfma_f32_16x16x32_f16(a0, Wb[ct * 64 + lane], acc[ct], 0, 0, 0);
      acc[ct] = __builtin_amdgcn_mfma_f32_16x16x32_f16(a1, Wb[(4 + ct) * 64 + lane], acc[ct], 0, 0, 0);
    }
  }
  // C/D: row = base + (lane>>4)*4 + rg, col = ct*16 + (lane&15)
  int obase = blockIdx.x * 64 + (wv << 4) + ((lane >> 4) << 2);
  int ocol = lane & 15;
#pragma unroll
  for (int ct = 0; ct < 4; ++ct) {
    int col = ct * 16 + ocol;
    float ea = (MODE == 0) ? epA[col] : 0.f;
    float eb = epB[col];
#pragma unroll
    for (int rg = 0; rg < 4; ++rg) {
      int r = obase + rg;
      if (r < N) {
        if (MODE == 0) {
          float v = fmaxf(fmaf(acc[ct][rg], ea, eb), 0.f);
          outh[((size_t)r << 6) + col] = (_Float16)v;
        } else {
          outf[((size_t)r << 6) + col] = acc[ct][rg] + eb;
        }
      }
    }
  }
}

// ---------------- round-1 fallback (small ws) ----------------
__global__ __launch_bounds__(256) void scale_w1(
    const float* __restrict__ w1, const float* __restrict__ gate,
    float* __restrict__ w1g)
{
  int b = blockIdx.x & 3, k = blockIdx.x >> 2;
  const float* src = w1 + ((size_t)k << 12);
  float* dst = w1g + (((size_t)(b * KK + k)) << 12);
  const float* g = gate + (b << 6);
  for (int it = 0; it < 16; ++it) {
    int pos = it * 256 + threadIdx.x;
    int ci = pos >> 6;
    dst[pos] = g[ci] * src[pos];
  }
}

template <int MODE>
__global__ __launch_bounds__(256) void spconv_kernel(
    const float* __restrict__ x, const int* __restrict__ nbr,
    const int* __restrict__ bidx, const float* __restrict__ W,
    const float* __restrict__ ep_a, const float* __restrict__ ep_b,
    float* __restrict__ out, int N)
{
  int wid = (int)((blockIdx.x * 256u + threadIdx.x) >> 6);
  if (wid >= N) return;
  int lane = threadIdx.x & 63;
  int n = __builtin_amdgcn_readfirstlane(wid);
  const float* Wb = W;
  if (MODE == 0) {
    int b = __builtin_amdgcn_readfirstlane(bidx[n]);
    Wb += (size_t)b * (KK * C * C);
  }
  float acc = 0.f;
#pragma unroll 1
  for (int k = 0; k < KK; ++k) {
    int idx = __builtin_amdgcn_readfirstlane(nbr[(size_t)k * N + n]);
    if (idx < 0) continue;
    const float* xr = x + ((size_t)idx << 6);
    const float* wr = Wb + (k << 12) + lane;
#pragma unroll
    for (int ci = 0; ci < C; ++ci) acc = fmaf(xr[ci], wr[ci << 6], acc);
  }
  float r;
  if (MODE == 0) r = fmaxf(fmaf(acc, ep_a[lane], ep_b[lane]), 0.f);
  else           r = acc + ep_b[lane];
  out[((size_t)n << 6) + lane] = r;
}

extern "C" void kernel_launch(void* const* d_in, const int* in_sizes, int n_in,
                              void* d_out, int out_size, void* d_ws, size_t ws_size,
                              hipStream_t stream) {
  const float* feats   = (const float*)d_in[0];
  const int*   nbr     = (const int*)  d_in[1];
  const int*   bidx    = (const int*)  d_in[2];
  const float* w_fc1   = (const float*)d_in[3];
  const float* b_fc1   = (const float*)d_in[4];
  const float* w_fc2   = (const float*)d_in[5];
  const float* b_fc2   = (const float*)d_in[6];
  const float* w_conv1 = (const float*)d_in[7];
  const float* bn_gamma= (const float*)d_in[8];
  const float* bn_beta = (const float*)d_in[9];
  const float* bn_mean = (const float*)d_in[10];
  const float* bn_var  = (const float*)d_in[11];
  const float* w_conv2 = (const float*)d_in[12];
  const float* b_conv2 = (const float*)d_in[13];

  int N = in_sizes[0] / C;
  float* ws      = (float*)d_ws;
  float* pooled  = ws;
  float* counts  = ws + 256;
  float* gate    = ws + 260;
  float* bnscale = ws + 516;
  float* bnshift = ws + 580;
  float* out     = (float*)d_out;

  size_t need = ((size_t)XG_OFF + (size_t)N * 64) * 4ull;   // Wf + xg + h2

  if (ws_size >= need) {
    _Float16* Wf1 = (_Float16*)(ws + 1024);
    _Float16* Wf2 = (_Float16*)(ws + 56320);
    _Float16* xg  = (_Float16*)(ws + XG_OFF);
    _Float16* h2  = (_Float16*)(ws + XG_OFF + (size_t)N * 32);

    hipLaunchKernelGGL(init_ws, dim3(4), dim3(256), 0, stream, ws);
    hipLaunchKernelGGL(pool_kernel, dim3(1024), dim3(256), 0, stream,
                       (const float4*)feats, bidx, pooled, counts, N);
    hipLaunchKernelGGL(gate_kernel, dim3(1), dim3(256), 0, stream,
                       pooled, counts, w_fc1, b_fc1, w_fc2, b_fc2,
                       bn_gamma, bn_beta, bn_mean, bn_var, gate, bnscale, bnshift);
    hipLaunchKernelGGL(w_pack, dim3(2 * KK), dim3(256), 0, stream,
                       w_conv1, w_conv2, Wf1, Wf2);
    hipLaunchKernelGGL(xg_pack, dim3(2048), dim3(256), 0, stream,
                       feats, bidx, gate, xg, (long)N * 8);
    // conv1: gather xg, MFMA over k, BN+ReLU epilogue -> h2 (f16)
    hipLaunchKernelGGL((conv_fused<0>), dim3((N + 63) / 64), dim3(256), 0, stream,
                       xg, Wf1, nbr, bnscale, bnshift, h2, nullptr, N);
    // conv2: gather h2, MFMA over k, +bias epilogue -> out (f32)
    hipLaunchKernelGGL((conv_fused<1>), dim3((N + 63) / 64), dim3(256), 0, stream,
                       h2, Wf2, nbr, nullptr, b_conv2, nullptr, out, N);
  } else {
    // round-1 fallback path
    float* w1g = ws + 1024;
    float* h   = ws + 1024 + BB * KK * C * C;
    hipLaunchKernelGGL(init_ws, dim3(4), dim3(256), 0, stream, ws);
    hipLaunchKernelGGL(pool_kernel, dim3(1024), dim3(256), 0, stream,
                       (const float4*)feats, bidx, pooled, counts, N);
    hipLaunchKernelGGL(gate_kernel, dim3(1), dim3(256), 0, stream,
                       pooled, counts, w_fc1, b_fc1, w_fc2, b_fc2,
                       bn_gamma, bn_beta, bn_mean, bn_var, gate, bnscale, bnshift);
    hipLaunchKernelGGL(scale_w1, dim3(KK * BB), dim3(256), 0, stream,
                       w_conv1, gate, w1g);
    hipLaunchKernelGGL((spconv_kernel<0>), dim3((N + 3) / 4), dim3(256), 0, stream,
                       feats, nbr, bidx, w1g, bnscale, bnshift, h, N);
    hipLaunchKernelGGL((spconv_kernel<1>), dim3((N + 3) / 4), dim3(256), 0, stream,
                       h, nbr, bidx, w_conv2, nullptr, b_conv2, out, N);
  }
}

// Round 12
// 968.567 us; speedup vs baseline: 1.0069x; 1.0069x over previous
//
#include <hip/hip_runtime.h>

#define C  64
#define KK 27
#define BB 4

typedef _Float16 h8 __attribute__((ext_vector_type(8)));
typedef float    f4 __attribute__((ext_vector_type(4)));

// ===================== fast-path ws layout (float offsets) =====================
//      0 : pooled[256]
//    256 : counts[4]
//    260 : gate[256]
//    516 : bnscale[64]
//    580 : bnshift[64]
//   1024 : Wf1[27*4096 halfs]  (55296 floats)
//  56320 : Wf2[27*4096 halfs]  (55296 floats)
// 114688 : xg[N*64 halfs]  (N*32 floats)
// 114688+N*32 : h2[N*64 halfs]  (N*32 floats)
#define XG_OFF 114688

__global__ __launch_bounds__(256) void init_ws(float* ws) {
  int t = blockIdx.x * 256 + threadIdx.x;
  if (t < 1024) ws[t] = 0.f;
}

// Grid-strided pooling: 16 threads per point row, float4 loads, shuffle+LDS reduce.
__global__ __launch_bounds__(256) void pool_kernel(
    const float4* __restrict__ x4, const int* __restrict__ bidx,
    float* __restrict__ pooled, float* __restrict__ counts, int N)
{
  int t = threadIdx.x;
  int g = t & 15;
  int rowInBlk = t >> 4;
  int lane = t & 63, wv = t >> 6;
  float4 acc[BB];
#pragma unroll
  for (int b = 0; b < BB; ++b) acc[b] = make_float4(0.f, 0.f, 0.f, 0.f);
  int cnt[BB] = {0, 0, 0, 0};
  for (int n = blockIdx.x * 16 + rowInBlk; n < N; n += gridDim.x * 16) {
    int b = bidx[n];
    float4 v = x4[((size_t)n << 4) + g];
    if (b == 0)      { acc[0].x += v.x; acc[0].y += v.y; acc[0].z += v.z; acc[0].w += v.w; }
    else if (b == 1) { acc[1].x += v.x; acc[1].y += v.y; acc[1].z += v.z; acc[1].w += v.w; }
    else if (b == 2) { acc[2].x += v.x; acc[2].y += v.y; acc[2].z += v.z; acc[2].w += v.w; }
    else             { acc[3].x += v.x; acc[3].y += v.y; acc[3].z += v.z; acc[3].w += v.w; }
    if (g == 0) {
      if (b == 0) cnt[0]++; else if (b == 1) cnt[1]++;
      else if (b == 2) cnt[2]++; else cnt[3]++;
    }
  }
#pragma unroll
  for (int b = 0; b < BB; ++b) {
    acc[b].x += __shfl_xor(acc[b].x, 16); acc[b].y += __shfl_xor(acc[b].y, 16);
    acc[b].z += __shfl_xor(acc[b].z, 16); acc[b].w += __shfl_xor(acc[b].w, 16);
    acc[b].x += __shfl_xor(acc[b].x, 32); acc[b].y += __shfl_xor(acc[b].y, 32);
    acc[b].z += __shfl_xor(acc[b].z, 32); acc[b].w += __shfl_xor(acc[b].w, 32);
    cnt[b] += __shfl_xor(cnt[b], 16);
    cnt[b] += __shfl_xor(cnt[b], 32);
  }
  __shared__ float red[4][BB][16][4];
  __shared__ int cred[4][BB];
  if (lane < 16) {
#pragma unroll
    for (int b = 0; b < BB; ++b) {
      red[wv][b][lane][0] = acc[b].x; red[wv][b][lane][1] = acc[b].y;
      red[wv][b][lane][2] = acc[b].z; red[wv][b][lane][3] = acc[b].w;
    }
    if (lane == 0) {
#pragma unroll
      for (int b = 0; b < BB; ++b) cred[wv][b] = cnt[b];
    }
  }
  __syncthreads();
  {
    int b = t >> 6, rem = t & 63;
    int gg = rem >> 2, comp = rem & 3;
    float s = red[0][b][gg][comp] + red[1][b][gg][comp] +
              red[2][b][gg][comp] + red[3][b][gg][comp];
    if (s != 0.f) atomicAdd(&pooled[b * C + (gg << 2) + comp], s);
  }
  if (t < BB) {
    int s = cred[0][t] + cred[1][t] + cred[2][t] + cred[3][t];
    if (s) atomicAdd(&counts[t], (float)s);
  }
}

__global__ __launch_bounds__(256) void gate_kernel(
    const float* __restrict__ pooled, const float* __restrict__ counts,
    const float* __restrict__ w_fc1, const float* __restrict__ b_fc1,
    const float* __restrict__ w_fc2, const float* __restrict__ b_fc2,
    const float* __restrict__ bn_gamma, const float* __restrict__ bn_beta,
    const float* __restrict__ bn_mean, const float* __restrict__ bn_var,
    float* __restrict__ gate, float* __restrict__ bnscale, float* __restrict__ bnshift)
{
  __shared__ float mean[BB * C];
  __shared__ float hh[BB * 16];
  int t = threadIdx.x;
  { int b = t >> 6; mean[t] = pooled[t] / counts[b]; }
  __syncthreads();
  if (t < BB * 16) {
    int b = t >> 4, r = t & 15;
    float s = b_fc1[r];
    for (int c = 0; c < C; ++c) s += mean[b * C + c] * w_fc1[c * 16 + r];
    hh[t] = fmaxf(s, 0.f);
  }
  __syncthreads();
  {
    int b = t >> 6, c = t & 63;
    float s = b_fc2[c];
    for (int r = 0; r < 16; ++r) s += hh[b * 16 + r] * w_fc2[r * 64 + c];
    gate[t] = 1.f / (1.f + expf(-s));
  }
  if (t < C) {
    float sc = bn_gamma[t] * rsqrtf(bn_var[t] + 1e-5f);
    bnscale[t] = sc;
    bnshift[t] = bn_beta[t] - bn_mean[t] * sc;
  }
}

// ---------------- pack W into f16 fragment-major layout ----------------
__global__ __launch_bounds__(256) void w_pack(
    const float* __restrict__ W1, const float* __restrict__ W2,
    _Float16* __restrict__ Wf1, _Float16* __restrict__ Wf2)
{
  int kk = blockIdx.x;
  const float* src = (kk < KK) ? (W1 + ((size_t)kk << 12)) : (W2 + ((size_t)(kk - KK) << 12));
  _Float16* dst = (kk < KK) ? (Wf1 + ((size_t)kk << 12)) : (Wf2 + ((size_t)(kk - KK) << 12));
  int t = threadIdx.x;
  for (int e = 0; e < 16; ++e) {
    int idx = e * 256 + t;
    int ci = idx >> 6, co = idx & 63;
    int kt = ci >> 5, i = ci & 7, lh = (ci >> 3) & 3, ct = co >> 4, col = co & 15;
    int lane = lh * 16 + col;
    dst[((kt * 4 + ct) * 64 + lane) * 8 + i] = (_Float16)src[idx];
  }
}

// ---------------- materialize gated feats as f16 ----------------
__global__ __launch_bounds__(256) void xg_pack(
    const float* __restrict__ feats, const int* __restrict__ bidx,
    const float* __restrict__ gate, _Float16* __restrict__ xg, long nchunks)
{
  long i = (long)blockIdx.x * 256 + threadIdx.x;
  long stride = (long)gridDim.x * 256;
  for (; i < nchunks; i += stride) {
    long row = i >> 3; int c8 = (int)(i & 7) << 3;
    const float* x = feats + (row << 6) + c8;
    const float* g = gate + ((size_t)(bidx[row]) << 6) + c8;
    float4 v0 = *(const float4*)x;
    float4 v1 = *(const float4*)(x + 4);
    float4 g0 = *(const float4*)g;
    float4 g1 = *(const float4*)(g + 4);
    h8 o;
    o[0] = (_Float16)(v0.x * g0.x); o[1] = (_Float16)(v0.y * g0.y);
    o[2] = (_Float16)(v0.z * g0.z); o[3] = (_Float16)(v0.w * g0.w);
    o[4] = (_Float16)(v1.x * g1.x); o[5] = (_Float16)(v1.y * g1.y);
    o[6] = (_Float16)(v1.z * g1.z); o[7] = (_Float16)(v1.w * g1.w);
    *(h8*)(xg + (row << 6) + c8) = o;
  }
}

// ---------------- fused sparse-conv, 3-stage software pipeline ----------------
// MODE 0: conv1 — src = xg (gated f16), epilogue BN+ReLU -> h2 (f16)
// MODE 1: conv2 — src = h2, epilogue +bias -> out (f32)
template <int MODE>
__global__ __launch_bounds__(256) void conv_fused(
    const _Float16* __restrict__ src, const _Float16* __restrict__ Wf,
    const int* __restrict__ nbr, const float* __restrict__ epA,
    const float* __restrict__ epB, _Float16* __restrict__ outh,
    float* __restrict__ outf, int N)
{
  int t = threadIdx.x, wv = t >> 6, lane = t & 63;
  int row = blockIdx.x * 64 + (wv << 4) + (lane & 15);   // A-operand dst row
  int koff = (lane >> 4) << 3;                            // K-slice within fragment
  bool inb = row < N;
  // ---- Phase 1: all 27 nbr loads in flight at once; wave-uniform active mask ----
  unsigned amask = 0;
  {
    int idxs[KK];
#pragma unroll
    for (int k = 0; k < KK; ++k)
      idxs[k] = inb ? nbr[(size_t)k * N + row] : -1;
#pragma unroll
    for (int k = 0; k < KK; ++k)
      if (__ballot(idxs[k] >= 0) != 0ull) amask |= (1u << k);
  }
  f4 acc[4];
#pragma unroll
  for (int ct = 0; ct < 4; ++ct) acc[ct] = (f4){0.f, 0.f, 0.f, 0.f};

#define POPK(kv) { kv = m ? (int)__builtin_ctz(m) : -1; if (kv >= 0) m &= m - 1; }
#define LDIDX(iv, kv) { iv = (kv >= 0 && inb) ? nbr[(size_t)(kv) * N + row] : -1; }
#define GATH(Aa, Ab, iv) { \
    if (iv >= 0) { const _Float16* xr = src + ((size_t)(iv) << 6); \
      Aa = *(const h8*)(xr + koff); Ab = *(const h8*)(xr + 32 + koff); } \
    else { Aa = (h8){}; Ab = (h8){}; } }

  unsigned m = amask;
  int k0, k1, k2, k3;
  POPK(k0); POPK(k1); POPK(k2); POPK(k3);
  int i0, i1, i2;
  LDIDX(i0, k0); LDIDX(i1, k1); LDIDX(i2, k2);   // all from L1/L2 (phase-1 warm)
  h8 A0a, A0b, A1a, A1b;
  GATH(A0a, A0b, i0);                             // stage-0 gather (prologue)
  if (k1 >= 0) { GATH(A1a, A1b, i1); } else { A1a = (h8){}; A1b = (h8){}; }
  // ---- Steady state: idx 3 ahead, gather 2 ahead, compute now ----
  while (k0 >= 0) {
    int i3; LDIDX(i3, k3);
    h8 A2a = {}, A2b = {};
    if (k2 >= 0) { GATH(A2a, A2b, i2); }
    const h8* Wb = (const h8*)(Wf + ((size_t)k0 << 12));
#pragma unroll
    for (int ct = 0; ct < 4; ++ct) {
      acc[ct] = __builtin_amdgcn_mfma_f32_16x16x32_f16(A0a, Wb[ct * 64 + lane], acc[ct], 0, 0, 0);
      acc[ct] = __builtin_amdgcn_mfma_f32_16x16x32_f16(A0b, Wb[(4 + ct) * 64 + lane], acc[ct], 0, 0, 0);
    }
    A0a = A1a; A0b = A1b; A1a = A2a; A1b = A2b;
    i2 = i3;
    k0 = k1; k1 = k2; k2 = k3;
    POPK(k3);
  }
#undef POPK
#undef LDIDX
#undef GATH
  // C/D: row = base + (lane>>4)*4 + rg, col = ct*16 + (lane&15)
  int obase = blockIdx.x * 64 + (wv << 4) + ((lane >> 4) << 2);
  int ocol = lane & 15;
#pragma unroll
  for (int ct = 0; ct < 4; ++ct) {
    int col = ct * 16 + ocol;
    float ea = (MODE == 0) ? epA[col] : 0.f;
    float eb = epB[col];
#pragma unroll
    for (int rg = 0; rg < 4; ++rg) {
      int r = obase + rg;
      if (r < N) {
        if (MODE == 0) {
          float v = fmaxf(fmaf(acc[ct][rg], ea, eb), 0.f);
          outh[((size_t)r << 6) + col] = (_Float16)v;
        } else {
          outf[((size_t)r << 6) + col] = acc[ct][rg] + eb;
        }
      }
    }
  }
}

// ---------------- round-1 fallback (small ws) ----------------
__global__ __launch_bounds__(256) void scale_w1(
    const float* __restrict__ w1, const float* __restrict__ gate,
    float* __restrict__ w1g)
{
  int b = blockIdx.x & 3, k = blockIdx.x >> 2;
  const float* src = w1 + ((size_t)k << 12);
  float* dst = w1g + (((size_t)(b * KK + k)) << 12);
  const float* g = gate + (b << 6);
  for (int it = 0; it < 16; ++it) {
    int pos = it * 256 + threadIdx.x;
    int ci = pos >> 6;
    dst[pos] = g[ci] * src[pos];
  }
}

template <int MODE>
__global__ __launch_bounds__(256) void spconv_kernel(
    const float* __restrict__ x, const int* __restrict__ nbr,
    const int* __restrict__ bidx, const float* __restrict__ W,
    const float* __restrict__ ep_a, const float* __restrict__ ep_b,
    float* __restrict__ out, int N)
{
  int wid = (int)((blockIdx.x * 256u + threadIdx.x) >> 6);
  if (wid >= N) return;
  int lane = threadIdx.x & 63;
  int n = __builtin_amdgcn_readfirstlane(wid);
  const float* Wb = W;
  if (MODE == 0) {
    int b = __builtin_amdgcn_readfirstlane(bidx[n]);
    Wb += (size_t)b * (KK * C * C);
  }
  float acc = 0.f;
#pragma unroll 1
  for (int k = 0; k < KK; ++k) {
    int idx = __builtin_amdgcn_readfirstlane(nbr[(size_t)k * N + n]);
    if (idx < 0) continue;
    const float* xr = x + ((size_t)idx << 6);
    const float* wr = Wb + (k << 12) + lane;
#pragma unroll
    for (int ci = 0; ci < C; ++ci) acc = fmaf(xr[ci], wr[ci << 6], acc);
  }
  float r;
  if (MODE == 0) r = fmaxf(fmaf(acc, ep_a[lane], ep_b[lane]), 0.f);
  else           r = acc + ep_b[lane];
  out[((size_t)n << 6) + lane] = r;
}

extern "C" void kernel_launch(void* const* d_in, const int* in_sizes, int n_in,
                              void* d_out, int out_size, void* d_ws, size_t ws_size,
                              hipStream_t stream) {
  const float* feats   = (const float*)d_in[0];
  const int*   nbr     = (const int*)  d_in[1];
  const int*   bidx    = (const int*)  d_in[2];
  const float* w_fc1   = (const float*)d_in[3];
  const float* b_fc1   = (const float*)d_in[4];
  const float* w_fc2   = (const float*)d_in[5];
  const float* b_fc2   = (const float*)d_in[6];
  const float* w_conv1 = (const float*)d_in[7];
  const float* bn_gamma= (const float*)d_in[8];
  const float* bn_beta = (const float*)d_in[9];
  const float* bn_mean = (const float*)d_in[10];
  const float* bn_var  = (const float*)d_in[11];
  const float* w_conv2 = (const float*)d_in[12];
  const float* b_conv2 = (const float*)d_in[13];

  int N = in_sizes[0] / C;
  float* ws      = (float*)d_ws;
  float* pooled  = ws;
  float* counts  = ws + 256;
  float* gate    = ws + 260;
  float* bnscale = ws + 516;
  float* bnshift = ws + 580;
  float* out     = (float*)d_out;

  size_t need = ((size_t)XG_OFF + (size_t)N * 64) * 4ull;   // Wf + xg + h2

  if (ws_size >= need) {
    _Float16* Wf1 = (_Float16*)(ws + 1024);
    _Float16* Wf2 = (_Float16*)(ws + 56320);
    _Float16* xg  = (_Float16*)(ws + XG_OFF);
    _Float16* h2  = (_Float16*)(ws + XG_OFF + (size_t)N * 32);

    hipLaunchKernelGGL(init_ws, dim3(4), dim3(256), 0, stream, ws);
    hipLaunchKernelGGL(pool_kernel, dim3(1024), dim3(256), 0, stream,
                       (const float4*)feats, bidx, pooled, counts, N);
    hipLaunchKernelGGL(gate_kernel, dim3(1), dim3(256), 0, stream,
                       pooled, counts, w_fc1, b_fc1, w_fc2, b_fc2,
                       bn_gamma, bn_beta, bn_mean, bn_var, gate, bnscale, bnshift);
    hipLaunchKernelGGL(w_pack, dim3(2 * KK), dim3(256), 0, stream,
                       w_conv1, w_conv2, Wf1, Wf2);
    hipLaunchKernelGGL(xg_pack, dim3(2048), dim3(256), 0, stream,
                       feats, bidx, gate, xg, (long)N * 8);
    // conv1: gather xg, pipelined MFMA over active k, BN+ReLU -> h2 (f16)
    hipLaunchKernelGGL((conv_fused<0>), dim3((N + 63) / 64), dim3(256), 0, stream,
                       xg, Wf1, nbr, bnscale, bnshift, h2, nullptr, N);
    // conv2: gather h2, pipelined MFMA over active k, +bias -> out (f32)
    hipLaunchKernelGGL((conv_fused<1>), dim3((N + 63) / 64), dim3(256), 0, stream,
                       h2, Wf2, nbr, nullptr, b_conv2, nullptr, out, N);
  } else {
    // round-1 fallback path
    float* w1g = ws + 1024;
    float* h   = ws + 1024 + BB * KK * C * C;
    hipLaunchKernelGGL(init_ws, dim3(4), dim3(256), 0, stream, ws);
    hipLaunchKernelGGL(pool_kernel, dim3(1024), dim3(256), 0, stream,
                       (const float4*)feats, bidx, pooled, counts, N);
    hipLaunchKernelGGL(gate_kernel, dim3(1), dim3(256), 0, stream,
                       pooled, counts, w_fc1, b_fc1, w_fc2, b_fc2,
                       bn_gamma, bn_beta, bn_mean, bn_var, gate, bnscale, bnshift);
    hipLaunchKernelGGL(scale_w1, dim3(KK * BB), dim3(256), 0, stream,
                       w_conv1, gate, w1g);
    hipLaunchKernelGGL((spconv_kernel<0>), dim3((N + 3) / 4), dim3(256), 0, stream,
                       feats, nbr, bidx, w1g, bnscale, bnshift, h, N);
    hipLaunchKernelGGL((spconv_kernel<1>), dim3((N + 3) / 4), dim3(256), 0, stream,
                       h, nbr, bidx, w_conv2, nullptr, b_conv2, out, N);
  }
}

// Round 15
// 849.545 us; speedup vs baseline: 1.1479x; 1.1401x over previous
//
#include <hip/hip_runtime.h>

#define C  64
#define KK 27
#define BB 4

typedef _Float16 h8 __attribute__((ext_vector_type(8)));
typedef float    f4 __attribute__((ext_vector_type(4)));

// ===================== fast-path ws layout (float offsets) =====================
//      0 : pooled[256]
//    256 : counts[4]
//    260 : gate[256]
//    516 : bnscale[64]
//    580 : bnshift[64]
//   1024 : Wf1[27*4096 halfs]  (55296 floats)
//  56320 : Wf2[27*4096 halfs]  (55296 floats)
// 114688 : xg[(N+1)*64 halfs]
//        : h2[(N+1)*64 halfs]
#define XG_OFF 114688

__global__ __launch_bounds__(256) void init_ws(float* ws) {
  int t = blockIdx.x * 256 + threadIdx.x;
  if (t < 1024) ws[t] = 0.f;
}

// Grid-strided pooling: 16 threads per point row, float4 loads, shuffle+LDS reduce.
__global__ __launch_bounds__(256) void pool_kernel(
    const float4* __restrict__ x4, const int* __restrict__ bidx,
    float* __restrict__ pooled, float* __restrict__ counts, int N)
{
  int t = threadIdx.x;
  int g = t & 15;
  int rowInBlk = t >> 4;
  int lane = t & 63, wv = t >> 6;
  float4 acc[BB];
#pragma unroll
  for (int b = 0; b < BB; ++b) acc[b] = make_float4(0.f, 0.f, 0.f, 0.f);
  int cnt[BB] = {0, 0, 0, 0};
  for (int n = blockIdx.x * 16 + rowInBlk; n < N; n += gridDim.x * 16) {
    int b = bidx[n];
    float4 v = x4[((size_t)n << 4) + g];
    if (b == 0)      { acc[0].x += v.x; acc[0].y += v.y; acc[0].z += v.z; acc[0].w += v.w; }
    else if (b == 1) { acc[1].x += v.x; acc[1].y += v.y; acc[1].z += v.z; acc[1].w += v.w; }
    else if (b == 2) { acc[2].x += v.x; acc[2].y += v.y; acc[2].z += v.z; acc[2].w += v.w; }
    else             { acc[3].x += v.x; acc[3].y += v.y; acc[3].z += v.z; acc[3].w += v.w; }
    if (g == 0) {
      if (b == 0) cnt[0]++; else if (b == 1) cnt[1]++;
      else if (b == 2) cnt[2]++; else cnt[3]++;
    }
  }
#pragma unroll
  for (int b = 0; b < BB; ++b) {
    acc[b].x += __shfl_xor(acc[b].x, 16); acc[b].y += __shfl_xor(acc[b].y, 16);
    acc[b].z += __shfl_xor(acc[b].z, 16); acc[b].w += __shfl_xor(acc[b].w, 16);
    acc[b].x += __shfl_xor(acc[b].x, 32); acc[b].y += __shfl_xor(acc[b].y, 32);
    acc[b].z += __shfl_xor(acc[b].z, 32); acc[b].w += __shfl_xor(acc[b].w, 32);
    cnt[b] += __shfl_xor(cnt[b], 16);
    cnt[b] += __shfl_xor(cnt[b], 32);
  }
  __shared__ float red[4][BB][16][4];
  __shared__ int cred[4][BB];
  if (lane < 16) {
#pragma unroll
    for (int b = 0; b < BB; ++b) {
      red[wv][b][lane][0] = acc[b].x; red[wv][b][lane][1] = acc[b].y;
      red[wv][b][lane][2] = acc[b].z; red[wv][b][lane][3] = acc[b].w;
    }
    if (lane == 0) {
#pragma unroll
      for (int b = 0; b < BB; ++b) cred[wv][b] = cnt[b];
    }
  }
  __syncthreads();
  {
    int b = t >> 6, rem = t & 63;
    int gg = rem >> 2, comp = rem & 3;
    float s = red[0][b][gg][comp] + red[1][b][gg][comp] +
              red[2][b][gg][comp] + red[3][b][gg][comp];
    if (s != 0.f) atomicAdd(&pooled[b * C + (gg << 2) + comp], s);
  }
  if (t < BB) {
    int s = cred[0][t] + cred[1][t] + cred[2][t] + cred[3][t];
    if (s) atomicAdd(&counts[t], (float)s);
  }
}

__global__ __launch_bounds__(256) void gate_kernel(
    const float* __restrict__ pooled, const float* __restrict__ counts,
    const float* __restrict__ w_fc1, const float* __restrict__ b_fc1,
    const float* __restrict__ w_fc2, const float* __restrict__ b_fc2,
    const float* __restrict__ bn_gamma, const float* __restrict__ bn_beta,
    const float* __restrict__ bn_mean, const float* __restrict__ bn_var,
    float* __restrict__ gate, float* __restrict__ bnscale, float* __restrict__ bnshift)
{
  __shared__ float mean[BB * C];
  __shared__ float hh[BB * 16];
  int t = threadIdx.x;
  { int b = t >> 6; mean[t] = pooled[t] / counts[b]; }
  __syncthreads();
  if (t < BB * 16) {
    int b = t >> 4, r = t & 15;
    float s = b_fc1[r];
    for (int c = 0; c < C; ++c) s += mean[b * C + c] * w_fc1[c * 16 + r];
    hh[t] = fmaxf(s, 0.f);
  }
  __syncthreads();
  {
    int b = t >> 6, c = t & 63;
    float s = b_fc2[c];
    for (int r = 0; r < 16; ++r) s += hh[b * 16 + r] * w_fc2[r * 64 + c];
    gate[t] = 1.f / (1.f + expf(-s));
  }
  if (t < C) {
    float sc = bn_gamma[t] * rsqrtf(bn_var[t] + 1e-5f);
    bnscale[t] = sc;
    bnshift[t] = bn_beta[t] - bn_mean[t] * sc;
  }
}

// ---------------- pack W into f16 fragment-major layout; block 54 zeroes row N ----------------
__global__ __launch_bounds__(256) void w_pack(
    const float* __restrict__ W1, const float* __restrict__ W2,
    _Float16* __restrict__ Wf1, _Float16* __restrict__ Wf2,
    _Float16* __restrict__ xg, _Float16* __restrict__ h2, int N)
{
  int kk = blockIdx.x;
  int t = threadIdx.x;
  if (kk == 2 * KK) {          // zero-row maintenance: xg[N], h2[N]
    if (t < 64) {
      xg[((size_t)N << 6) + t] = (_Float16)0.f;
      h2[((size_t)N << 6) + t] = (_Float16)0.f;
    }
    return;
  }
  const float* src = (kk < KK) ? (W1 + ((size_t)kk << 12)) : (W2 + ((size_t)(kk - KK) << 12));
  _Float16* dst = (kk < KK) ? (Wf1 + ((size_t)kk << 12)) : (Wf2 + ((size_t)(kk - KK) << 12));
  for (int e = 0; e < 16; ++e) {
    int idx = e * 256 + t;
    int ci = idx >> 6, co = idx & 63;
    int kt = ci >> 5, i = ci & 7, lh = (ci >> 3) & 3, ct = co >> 4, col = co & 15;
    int lane = lh * 16 + col;
    dst[((kt * 4 + ct) * 64 + lane) * 8 + i] = (_Float16)src[idx];
  }
}

// ---------------- materialize gated feats as f16 ----------------
__global__ __launch_bounds__(256) void xg_pack(
    const float* __restrict__ feats, const int* __restrict__ bidx,
    const float* __restrict__ gate, _Float16* __restrict__ xg, long nchunks)
{
  long i = (long)blockIdx.x * 256 + threadIdx.x;
  long stride = (long)gridDim.x * 256;
  for (; i < nchunks; i += stride) {
    long row = i >> 3; int c8 = (int)(i & 7) << 3;
    const float* x = feats + (row << 6) + c8;
    const float* g = gate + ((size_t)(bidx[row]) << 6) + c8;
    float4 v0 = *(const float4*)x;
    float4 v1 = *(const float4*)(x + 4);
    float4 g0 = *(const float4*)g;
    float4 g1 = *(const float4*)(g + 4);
    h8 o;
    o[0] = (_Float16)(v0.x * g0.x); o[1] = (_Float16)(v0.y * g0.y);
    o[2] = (_Float16)(v0.z * g0.z); o[3] = (_Float16)(v0.w * g0.w);
    o[4] = (_Float16)(v1.x * g1.x); o[5] = (_Float16)(v1.y * g1.y);
    o[6] = (_Float16)(v1.z * g1.z); o[7] = (_Float16)(v1.w * g1.w);
    *(h8*)(xg + (row << 6) + c8) = o;
  }
}

// ---------------- fused sparse-conv: 32 rows/wave, branchless zero-row gathers ----------------
// MODE 0: conv1 — src = xg, epilogue BN+ReLU -> h2 (f16)
// MODE 1: conv2 — src = h2, epilogue +bias -> out (f32)
template <int MODE>
__global__ __launch_bounds__(256, 4) void conv_fused(
    const _Float16* __restrict__ src, const _Float16* __restrict__ Wf,
    const int* __restrict__ nbr, const float* __restrict__ epA,
    const float* __restrict__ epB, _Float16* __restrict__ outh,
    float* __restrict__ outf, int N)
{
  int t = threadIdx.x, wv = t >> 6, lane = t & 63;
  int rbase = blockIdx.x * 128 + (wv << 5);
  int row0 = rbase + (lane & 15);
  int row1 = row0 + 16;
  int rc0 = min(row0, N - 1);
  int rc1 = min(row1, N - 1);
  bool inb0 = row0 < N, inb1 = row1 < N;
  int koff = (lane >> 4) << 3;

  // ---- Phase 1: active-k masks per 16-row group (wave-uniform) ----
  unsigned gm0 = 0, gm1 = 0;
#pragma unroll
  for (int k = 0; k < KK; ++k) {
    int v = nbr[(size_t)k * N + rc0];
    if (__ballot(inb0 && v >= 0) != 0ull) gm0 |= (1u << k);
  }
#pragma unroll
  for (int k = 0; k < KK; ++k) {
    int v = nbr[(size_t)k * N + rc1];
    if (__ballot(inb1 && v >= 0) != 0ull) gm1 |= (1u << k);
  }
  gm0 = __builtin_amdgcn_readfirstlane(gm0);
  gm1 = __builtin_amdgcn_readfirstlane(gm1);
  unsigned am = gm0 | gm1;

  f4 acc0[4], acc1[4];
#pragma unroll
  for (int ct = 0; ct < 4; ++ct) { acc0[ct] = (f4){0,0,0,0}; acc1[ct] = (f4){0,0,0,0}; }

  // Unconditional gather set: invalid lanes read the zeroed row N (L1-hot).
  auto GSET = [&](int kv, h8& g0a, h8& g0b, h8& g1a, h8& g1b) {
    int kc = kv < 0 ? 0 : kv;
    int v0 = nbr[(size_t)kc * N + rc0];      // L1-hot (phase-1 warmed)
    int v1 = nbr[(size_t)kc * N + rc1];
    int s0 = (kv >= 0 && inb0 && v0 >= 0) ? v0 : N;
    int s1 = (kv >= 0 && inb1 && v1 >= 0) ? v1 : N;
    const _Float16* p0 = src + ((size_t)s0 << 6) + koff;
    const _Float16* p1 = src + ((size_t)s1 << 6) + koff;
    g0a = *(const h8*)p0; g0b = *(const h8*)(p0 + 32);
    g1a = *(const h8*)p1; g1b = *(const h8*)(p1 + 32);
  };

  unsigned m = am;
  int k0 = m ? (int)__builtin_ctz(m) : -1; if (k0 >= 0) m &= m - 1;
  int k1 = m ? (int)__builtin_ctz(m) : -1; if (k1 >= 0) m &= m - 1;
  h8 c0a, c0b, c1a, c1b, n0a, n0b, n1a, n1b;
  GSET(k0, c0a, c0b, c1a, c1b);
  while (k0 >= 0) {
    GSET(k1, n0a, n0b, n1a, n1b);          // next-k gathers in flight (unconditional)
    const h8* Wb = (const h8*)(Wf + ((size_t)k0 << 12));
    h8 b[8];
#pragma unroll
    for (int q = 0; q < 8; ++q) b[q] = Wb[q * 64 + lane];
    if ((gm0 >> k0) & 1) {
#pragma unroll
      for (int ct = 0; ct < 4; ++ct) {
        acc0[ct] = __builtin_amdgcn_mfma_f32_16x16x32_f16(c0a, b[ct], acc0[ct], 0, 0, 0);
        acc0[ct] = __builtin_amdgcn_mfma_f32_16x16x32_f16(c0b, b[4 + ct], acc0[ct], 0, 0, 0);
      }
    }
    if ((gm1 >> k0) & 1) {
#pragma unroll
      for (int ct = 0; ct < 4; ++ct) {
        acc1[ct] = __builtin_amdgcn_mfma_f32_16x16x32_f16(c1a, b[ct], acc1[ct], 0, 0, 0);
        acc1[ct] = __builtin_amdgcn_mfma_f32_16x16x32_f16(c1b, b[4 + ct], acc1[ct], 0, 0, 0);
      }
    }
    c0a = n0a; c0b = n0b; c1a = n1a; c1b = n1b;
    k0 = k1;
    k1 = m ? (int)__builtin_ctz(m) : -1; if (k1 >= 0) m &= m - 1;
  }

  // C/D: row = grpbase + (lane>>4)*4 + rg, col = ct*16 + (lane&15)
  int rsub = (lane >> 4) << 2;
  int ocol = lane & 15;
#pragma unroll
  for (int g = 0; g < 2; ++g) {
    int obase = rbase + g * 16 + rsub;
    f4* accp = g ? acc1 : acc0;
#pragma unroll
    for (int ct = 0; ct < 4; ++ct) {
      int col = ct * 16 + ocol;
      float ea = (MODE == 0) ? epA[col] : 0.f;
      float eb = epB[col];
#pragma unroll
      for (int rg = 0; rg < 4; ++rg) {
        int r = obase + rg;
        if (r < N) {
          if (MODE == 0) {
            float v = fmaxf(fmaf(accp[ct][rg], ea, eb), 0.f);
            outh[((size_t)r << 6) + col] = (_Float16)v;
          } else {
            outf[((size_t)r << 6) + col] = accp[ct][rg] + eb;
          }
        }
      }
    }
  }
}

// ---------------- round-1 fallback (small ws) ----------------
__global__ __launch_bounds__(256) void scale_w1(
    const float* __restrict__ w1, const float* __restrict__ gate,
    float* __restrict__ w1g)
{
  int b = blockIdx.x & 3, k = blockIdx.x >> 2;
  const float* src = w1 + ((size_t)k << 12);
  float* dst = w1g + (((size_t)(b * KK + k)) << 12);
  const float* g = gate + (b << 6);
  for (int it = 0; it < 16; ++it) {
    int pos = it * 256 + threadIdx.x;
    int ci = pos >> 6;
    dst[pos] = g[ci] * src[pos];
  }
}

template <int MODE>
__global__ __launch_bounds__(256) void spconv_kernel(
    const float* __restrict__ x, const int* __restrict__ nbr,
    const int* __restrict__ bidx, const float* __restrict__ W,
    const float* __restrict__ ep_a, const float* __restrict__ ep_b,
    float* __restrict__ out, int N)
{
  int wid = (int)((blockIdx.x * 256u + threadIdx.x) >> 6);
  if (wid >= N) return;
  int lane = threadIdx.x & 63;
  int n = __builtin_amdgcn_readfirstlane(wid);
  const float* Wb = W;
  if (MODE == 0) {
    int b = __builtin_amdgcn_readfirstlane(bidx[n]);
    Wb += (size_t)b * (KK * C * C);
  }
  float acc = 0.f;
#pragma unroll 1
  for (int k = 0; k < KK; ++k) {
    int idx = __builtin_amdgcn_readfirstlane(nbr[(size_t)k * N + n]);
    if (idx < 0) continue;
    const float* xr = x + ((size_t)idx << 6);
    const float* wr = Wb + (k << 12) + lane;
#pragma unroll
    for (int ci = 0; ci < C; ++ci) acc = fmaf(xr[ci], wr[ci << 6], acc);
  }
  float r;
  if (MODE == 0) r = fmaxf(fmaf(acc, ep_a[lane], ep_b[lane]), 0.f);
  else           r = acc + ep_b[lane];
  out[((size_t)n << 6) + lane] = r;
}

extern "C" void kernel_launch(void* const* d_in, const int* in_sizes, int n_in,
                              void* d_out, int out_size, void* d_ws, size_t ws_size,
                              hipStream_t stream) {
  const float* feats   = (const float*)d_in[0];
  const int*   nbr     = (const int*)  d_in[1];
  const int*   bidx    = (const int*)  d_in[2];
  const float* w_fc1   = (const float*)d_in[3];
  const float* b_fc1   = (const float*)d_in[4];
  const float* w_fc2   = (const float*)d_in[5];
  const float* b_fc2   = (const float*)d_in[6];
  const float* w_conv1 = (const float*)d_in[7];
  const float* bn_gamma= (const float*)d_in[8];
  const float* bn_beta = (const float*)d_in[9];
  const float* bn_mean = (const float*)d_in[10];
  const float* bn_var  = (const float*)d_in[11];
  const float* w_conv2 = (const float*)d_in[12];
  const float* b_conv2 = (const float*)d_in[13];

  int N = in_sizes[0] / C;
  float* ws      = (float*)d_ws;
  float* pooled  = ws;
  float* counts  = ws + 256;
  float* gate    = ws + 260;
  float* bnscale = ws + 516;
  float* bnshift = ws + 580;
  float* out     = (float*)d_out;

  size_t need = ((size_t)XG_OFF + ((size_t)N + 1) * 64) * 4ull;   // Wf + xg + h2 (N+1 rows each)

  if (ws_size >= need) {
    _Float16* Wf1 = (_Float16*)(ws + 1024);
    _Float16* Wf2 = (_Float16*)(ws + 56320);
    _Float16* xg  = (_Float16*)(ws + XG_OFF);
    _Float16* h2  = (_Float16*)(ws + XG_OFF + ((size_t)N + 1) * 32);

    hipLaunchKernelGGL(init_ws, dim3(4), dim3(256), 0, stream, ws);
    hipLaunchKernelGGL(pool_kernel, dim3(1024), dim3(256), 0, stream,
                       (const float4*)feats, bidx, pooled, counts, N);
    hipLaunchKernelGGL(gate_kernel, dim3(1), dim3(256), 0, stream,
                       pooled, counts, w_fc1, b_fc1, w_fc2, b_fc2,
                       bn_gamma, bn_beta, bn_mean, bn_var, gate, bnscale, bnshift);
    hipLaunchKernelGGL(w_pack, dim3(2 * KK + 1), dim3(256), 0, stream,
                       w_conv1, w_conv2, Wf1, Wf2, xg, h2, N);
    hipLaunchKernelGGL(xg_pack, dim3(2048), dim3(256), 0, stream,
                       feats, bidx, gate, xg, (long)N * 8);
    // conv1: gather xg (branchless), MFMA over active k, BN+ReLU -> h2 (f16)
    hipLaunchKernelGGL((conv_fused<0>), dim3((N + 127) / 128), dim3(256), 0, stream,
                       xg, Wf1, nbr, bnscale, bnshift, h2, nullptr, N);
    // conv2: gather h2 (branchless), MFMA over active k, +bias -> out (f32)
    hipLaunchKernelGGL((conv_fused<1>), dim3((N + 127) / 128), dim3(256), 0, stream,
                       h2, Wf2, nbr, nullptr, b_conv2, nullptr, out, N);
  } else {
    // round-1 fallback path
    float* w1g = ws + 1024;
    float* h   = ws + 1024 + BB * KK * C * C;
    hipLaunchKernelGGL(init_ws, dim3(4), dim3(256), 0, stream, ws);
    hipLaunchKernelGGL(pool_kernel, dim3(1024), dim3(256), 0, stream,
                       (const float4*)feats, bidx, pooled, counts, N);
    hipLaunchKernelGGL(gate_kernel, dim3(1), dim3(256), 0, stream,
                       pooled, counts, w_fc1, b_fc1, w_fc2, b_fc2,
                       bn_gamma, bn_beta, bn_mean, bn_var, gate, bnscale, bnshift);
    hipLaunchKernelGGL(scale_w1, dim3(KK * BB), dim3(256), 0, stream,
                       w_conv1, gate, w1g);
    hipLaunchKernelGGL((spconv_kernel<0>), dim3((N + 3) / 4), dim3(256), 0, stream,
                       feats, nbr, bidx, w1g, bnscale, bnshift, h, N);
    hipLaunchKernelGGL((spconv_kernel<1>), dim3((N + 3) / 4), dim3(256), 0, stream,
                       h, nbr, bidx, w_conv2, nullptr, b_conv2, out, N);
  }
}